// Round 9
// baseline (76.125 us; speedup 1.0000x reference)
//
#include <hip/hip_runtime.h>
#include <hip/hip_bf16.h>

typedef _Float16 half8 __attribute__((ext_vector_type(8)));
typedef float f32x16 __attribute__((ext_vector_type(16)));

constexpr int KC = 256;      // clusters
constexpr int DD = 64;       // feature dim
constexpr int NN = 262144;   // points
constexpr int GRID = 256;    // blocks; each owns 1024 cols
constexpr int NCH = 4;       // 32-col chunks per wave (contiguous 128-col wave window)

// out[k][n] = A[k] + (mu[k].x[n] - 0.5*x2[n]) * C[k]
// A[k] = alpha[k] - 32*logvar[k] - 0.5*m2[k]*C[k],  C[k] = exp(-logvar[k])

__global__ __launch_bounds__(512, 2)
void gmm_ll_kernel(const float* __restrict__ X,
                   const float* __restrict__ mu,
                   const float* __restrict__ logvar,
                   const float* __restrict__ alpha,
                   float* __restrict__ out)
{
    // mu in f16, XOR-swizzled chunks: row r (128 B = 8 chunks), chunk s at slot s^(r&7)
    __shared__ __align__(16) unsigned char smu[KC * 128];
    __shared__ float2 AC[KC];

    const int tid = threadIdx.x;

    // ---------- setup: threads 0..255 own one cluster each ----------
    if (tid < KC) {
        const float* mrow = mu + tid * DD;
        float m2 = 0.f;
        #pragma unroll
        for (int s = 0; s < 8; ++s) {
            float4 v0 = *(const float4*)(mrow + 8 * s);
            float4 v1 = *(const float4*)(mrow + 8 * s + 4);
            m2 += v0.x*v0.x + v0.y*v0.y + v0.z*v0.z + v0.w*v0.w
                + v1.x*v1.x + v1.y*v1.y + v1.z*v1.z + v1.w*v1.w;
            half8 hch = { (_Float16)v0.x, (_Float16)v0.y, (_Float16)v0.z, (_Float16)v0.w,
                          (_Float16)v1.x, (_Float16)v1.y, (_Float16)v1.z, (_Float16)v1.w };
            *(half8*)(smu + tid * 128 + ((s ^ (tid & 7)) * 16)) = hch;
        }
        float lv = logvar[tid];
        float Cv = __expf(-lv);
        AC[tid] = make_float2(alpha[tid] - 32.0f * lv - 0.5f * m2 * Cv, Cv);
    }

    const int l = tid & 63;
    const int w = tid >> 6;   // wave 0..7
    const int q = l & 31;     // column within 32-col chunk / mu row selector
    const int h = l >> 5;     // k-half selector

    // XCD-aware bijective swizzle (GRID % 8 == 0): contiguous col range per XCD
    const int b  = blockIdx.x;
    const int bs = (b & 7) * (GRID / 8) + (b >> 3);
    // wave owns a CONTIGUOUS 128-col window; ch steps 32 cols inside it
    const int col0 = bs * 1024 + w * 128 + q;

    // ---------- X fragments for all chunks, kept in registers ----------
    half8 bf[NCH][4];
    float hx2[NCH];
    #pragma unroll
    for (int ch = 0; ch < NCH; ++ch) {
        const float* xr = X + (size_t)(col0 + ch * 32) * DD;
        float p = 0.f;
        #pragma unroll
        for (int kk = 0; kk < 4; ++kk) {
            float4 v0 = *(const float4*)(xr + kk * 16 + h * 8);
            float4 v1 = *(const float4*)(xr + kk * 16 + h * 8 + 4);
            p += v0.x*v0.x + v0.y*v0.y + v0.z*v0.z + v0.w*v0.w
               + v1.x*v1.x + v1.y*v1.y + v1.z*v1.z + v1.w*v1.w;
            bf[ch][kk] = { (_Float16)v0.x, (_Float16)v0.y, (_Float16)v0.z, (_Float16)v0.w,
                           (_Float16)v1.x, (_Float16)v1.y, (_Float16)v1.z, (_Float16)v1.w };
        }
        p += __shfl_xor(p, 32, 64);   // partner lane holds the other k-half
        hx2[ch] = 0.5f * p;
    }
    __syncthreads();

    #pragma unroll 1
    for (int c = 0; c < 8; ++c) {
        const unsigned rbase = (unsigned)(32 * c + q) * 128u;
        const unsigned sw = (unsigned)(q & 7);
        half8 af[4];
        #pragma unroll
        for (int kk = 0; kk < 4; ++kk)
            af[kk] = *(const half8*)(smu + rbase + ((((unsigned)(2 * kk + h)) ^ sw) * 16));

        f32x16 acc[NCH];
        #pragma unroll
        for (int ch = 0; ch < NCH; ++ch) {
            acc[ch] = (f32x16){0.f,0.f,0.f,0.f,0.f,0.f,0.f,0.f,
                               0.f,0.f,0.f,0.f,0.f,0.f,0.f,0.f};
            #pragma unroll
            for (int kk = 0; kk < 4; ++kk)
                acc[ch] = __builtin_amdgcn_mfma_f32_32x32x16_f16(af[kk], bf[ch][kk], acc[ch], 0, 0, 0);
        }

        // D layout: col = lane&31, row = (reg&3) + 8*(reg>>2) + 4*(lane>>5)
        // ch-inner stores: 4 back-to-back ADJACENT full 128-B lines = 512-B
        // contiguous run per (row, wave); nontemporal (out never re-read)
        #pragma unroll
        for (int g = 0; g < 4; ++g) {
            const int Rb = 32 * c + 8 * g + 4 * h;
            #pragma unroll
            for (int j = 0; j < 4; ++j) {
                const float2 ac = AC[Rb + j];
                float* po = out + (size_t)(Rb + j) * NN + col0;
                #pragma unroll
                for (int ch = 0; ch < NCH; ++ch)
                    __builtin_nontemporal_store(
                        ac.x + (acc[ch][4 * g + j] - hx2[ch]) * ac.y, &po[ch * 32]);
            }
        }
    }
}

extern "C" void kernel_launch(void* const* d_in, const int* in_sizes, int n_in,
                              void* d_out, int out_size, void* d_ws, size_t ws_size,
                              hipStream_t stream)
{
    const float* X  = (const float*)d_in[0];
    const float* mu = (const float*)d_in[1];
    const float* lv = (const float*)d_in[2];
    const float* al = (const float*)d_in[3];
    float* out = (float*)d_out;
    gmm_ll_kernel<<<GRID, 512, 0, stream>>>(X, mu, lv, al, out);
}

// Round 10
// 73.108 us; speedup vs baseline: 1.0413x; 1.0413x over previous
//
#include <hip/hip_runtime.h>
#include <hip/hip_bf16.h>

typedef _Float16 half8 __attribute__((ext_vector_type(8)));
typedef float f32x16 __attribute__((ext_vector_type(16)));

typedef const __attribute__((address_space(1))) unsigned int glb_u32;
typedef __attribute__((address_space(3))) unsigned int lds_u32;

constexpr int KC = 256;      // clusters
constexpr int DD = 64;       // feature dim
constexpr int NN = 262144;   // points
constexpr int GRID = 256;    // blocks; each owns NCH*256 = 1024 cols
constexpr int NCH = 4;       // column chunks per block (R8 layout: ch*256 + w*32 + q)

// out[k][n] = A[k] + (mu[k].x[n] - 0.5*x2[n]) * C[k]
// A[k] = alpha[k] - 32*logvar[k] - 0.5*m2[k]*C[k],  C[k] = exp(-logvar[k])

__global__ __launch_bounds__(512, 2)
void gmm_ll_kernel(const float* __restrict__ X,
                   const float* __restrict__ mu,
                   const float* __restrict__ logvar,
                   const float* __restrict__ alpha,
                   float* __restrict__ out)
{
    // mu in f16, XOR-swizzled chunks: row r (128 B = 8 chunks), chunk s at slot s^(r&7)
    __shared__ __align__(16) unsigned char smu[KC * 128];
    __shared__ float2 AC[KC];
    // per-wave 8-KB X staging buffers (32 cols x 256 B), granule-swizzled at the SOURCE
    __shared__ __align__(16) unsigned char stage[8 * 8192];

    const int tid = threadIdx.x;

    // ---------- setup: threads 0..255 own one cluster each ----------
    if (tid < KC) {
        const float* mrow = mu + tid * DD;
        float m2 = 0.f;
        #pragma unroll
        for (int s = 0; s < 8; ++s) {
            float4 v0 = *(const float4*)(mrow + 8 * s);
            float4 v1 = *(const float4*)(mrow + 8 * s + 4);
            m2 += v0.x*v0.x + v0.y*v0.y + v0.z*v0.z + v0.w*v0.w
                + v1.x*v1.x + v1.y*v1.y + v1.z*v1.z + v1.w*v1.w;
            half8 hch = { (_Float16)v0.x, (_Float16)v0.y, (_Float16)v0.z, (_Float16)v0.w,
                          (_Float16)v1.x, (_Float16)v1.y, (_Float16)v1.z, (_Float16)v1.w };
            *(half8*)(smu + tid * 128 + ((s ^ (tid & 7)) * 16)) = hch;
        }
        float lv = logvar[tid];
        float Cv = __expf(-lv);
        AC[tid] = make_float2(alpha[tid] - 32.0f * lv - 0.5f * m2 * Cv, Cv);
    }
    __syncthreads();

    const int l = tid & 63;
    const int w = tid >> 6;   // wave 0..7
    const int q = l & 31;     // column within 32-col window / mu row selector
    const int h = l >> 5;     // k-half selector

    // XCD-aware bijective swizzle (GRID % 8 == 0)
    const int b  = blockIdx.x;
    const int bs = (b & 7) * (GRID / 8) + (b >> 3);
    const int col0 = bs * 1024 + w * 32 + q;          // R8 layout (ch adds ch*256)

    unsigned char* sbuf = stage + w * 8192;           // wave-private

    // ---------- X fragments for all chunks via coalesced global_load_lds ----------
    // LDS layout per col t (256 B row, 16-B granules): slot u holds global granule
    // u^(t&7) -> fragment granule g of col q is at slot g^(q&7). Source-side swizzle
    // keeps the LDS destination linear (global_load_lds requirement).
    half8 bf[NCH][4];
    float hx2[NCH];
    #pragma unroll 1
    for (int ch = 0; ch < NCH; ++ch) {
        const int colw = bs * 1024 + ch * 256 + w * 32;        // first col of wave window
        const unsigned char* gsrc = (const unsigned char*)(X + (size_t)colw * DD);
        #pragma unroll
        for (int j = 0; j < 8; ++j) {
            const int gran = j * 64 + l;                        // linear 16-B granule
            const int t = gran >> 4;                            // col within window
            const int u = gran & 15;                            // granule slot
            const int sg = t * 16 + (u ^ (t & 7));              // swizzled source granule
            __builtin_amdgcn_global_load_lds((glb_u32*)(gsrc + sg * 16),
                                             (lds_u32*)(sbuf + j * 1024),
                                             16, 0, 0);
        }
        asm volatile("s_waitcnt vmcnt(0)" ::: "memory");

        float p = 0.f;
        #pragma unroll
        for (int kk = 0; kk < 4; ++kk) {
            const int g1 = 4 * kk + 2 * h;
            float4 v0 = *(const float4*)(sbuf + q * 256 + ((g1 ^ (q & 7)) * 16));
            float4 v1 = *(const float4*)(sbuf + q * 256 + (((g1 + 1) ^ (q & 7)) * 16));
            p += v0.x*v0.x + v0.y*v0.y + v0.z*v0.z + v0.w*v0.w
               + v1.x*v1.x + v1.y*v1.y + v1.z*v1.z + v1.w*v1.w;
            bf[ch][kk] = { (_Float16)v0.x, (_Float16)v0.y, (_Float16)v0.z, (_Float16)v0.w,
                           (_Float16)v1.x, (_Float16)v1.y, (_Float16)v1.z, (_Float16)v1.w };
        }
        p += __shfl_xor(p, 32, 64);   // partner lane holds the other k-half
        hx2[ch] = 0.5f * p;
    }

    #pragma unroll 1
    for (int c = 0; c < 8; ++c) {
        const unsigned rbase = (unsigned)(32 * c + q) * 128u;
        const unsigned sw = (unsigned)(q & 7);
        half8 af[4];
        #pragma unroll
        for (int kk = 0; kk < 4; ++kk)
            af[kk] = *(const half8*)(smu + rbase + ((((unsigned)(2 * kk + h)) ^ sw) * 16));

        f32x16 acc[NCH];
        #pragma unroll
        for (int ch = 0; ch < NCH; ++ch) {
            acc[ch] = (f32x16){0.f,0.f,0.f,0.f,0.f,0.f,0.f,0.f,
                               0.f,0.f,0.f,0.f,0.f,0.f,0.f,0.f};
            #pragma unroll
            for (int kk = 0; kk < 4; ++kk)
                acc[ch] = __builtin_amdgcn_mfma_f32_32x32x16_f16(af[kk], bf[ch][kk], acc[ch], 0, 0, 0);
        }

        // D layout: col = lane&31, row = (reg&3) + 8*(reg>>2) + 4*(lane>>5)
        // R8 store order (g, j, ch): cross-wave-contiguous 1-KB line groups per slot,
        // 4-KB burst per k-row per block; nontemporal (out never re-read)
        #pragma unroll
        for (int g = 0; g < 4; ++g) {
            const int Rb = 32 * c + 8 * g + 4 * h;
            #pragma unroll
            for (int j = 0; j < 4; ++j) {
                const float2 ac = AC[Rb + j];
                float* po = out + (size_t)(Rb + j) * NN + col0;
                #pragma unroll
                for (int ch = 0; ch < NCH; ++ch)
                    __builtin_nontemporal_store(
                        ac.x + (acc[ch][4 * g + j] - hx2[ch]) * ac.y, &po[ch * 256]);
            }
        }
    }
}

extern "C" void kernel_launch(void* const* d_in, const int* in_sizes, int n_in,
                              void* d_out, int out_size, void* d_ws, size_t ws_size,
                              hipStream_t stream)
{
    const float* X  = (const float*)d_in[0];
    const float* mu = (const float*)d_in[1];
    const float* lv = (const float*)d_in[2];
    const float* al = (const float*)d_in[3];
    float* out = (float*)d_out;
    gmm_ll_kernel<<<GRID, 512, 0, stream>>>(X, mu, lv, al, out);
}

// Round 12
// 65.205 us; speedup vs baseline: 1.1675x; 1.1212x over previous
//
#include <hip/hip_runtime.h>
#include <hip/hip_bf16.h>

typedef _Float16 half8 __attribute__((ext_vector_type(8)));
typedef float f32x16 __attribute__((ext_vector_type(16)));

constexpr int KC = 256;      // clusters
constexpr int DD = 64;       // feature dim
constexpr int NN = 262144;   // points
constexpr int GRID = 256;    // blocks; each owns NCH*256 = 1024 cols
constexpr int NCH = 4;       // column chunks per block

// out[k][n] = A[k] + (mu[k].x[n] - 0.5*x2[n]) * C[k]
// A[k] = alpha[k] - 32*logvar[k] - 0.5*m2[k]*C[k],  C[k] = exp(-logvar[k])

__global__ __launch_bounds__(512, 2)
void gmm_ll_kernel(const float* __restrict__ X,
                   const float* __restrict__ mu,
                   const float* __restrict__ logvar,
                   const float* __restrict__ alpha,
                   float* __restrict__ out)
{
    // mu in f16, XOR-swizzled chunks: row r (128 B = 8 chunks), chunk s at slot s^(r&7)
    __shared__ __align__(16) unsigned char smu[KC * 128];
    __shared__ float2 AC[KC];

    const int tid = threadIdx.x;

    // ---------- setup: threads 0..255 own one cluster each ----------
    if (tid < KC) {
        const float* mrow = mu + tid * DD;
        float m2 = 0.f;
        #pragma unroll
        for (int s = 0; s < 8; ++s) {
            float4 v0 = *(const float4*)(mrow + 8 * s);
            float4 v1 = *(const float4*)(mrow + 8 * s + 4);
            m2 += v0.x*v0.x + v0.y*v0.y + v0.z*v0.z + v0.w*v0.w
                + v1.x*v1.x + v1.y*v1.y + v1.z*v1.z + v1.w*v1.w;
            half8 hch = { (_Float16)v0.x, (_Float16)v0.y, (_Float16)v0.z, (_Float16)v0.w,
                          (_Float16)v1.x, (_Float16)v1.y, (_Float16)v1.z, (_Float16)v1.w };
            *(half8*)(smu + tid * 128 + ((s ^ (tid & 7)) * 16)) = hch;
        }
        float lv = logvar[tid];
        float Cv = __expf(-lv);
        AC[tid] = make_float2(alpha[tid] - 32.0f * lv - 0.5f * m2 * Cv, Cv);
    }

    const int l = tid & 63;
    const int w = tid >> 6;   // wave 0..7
    const int q = l & 31;     // column within 32-col window / mu row selector
    const int h = l >> 5;     // k-half selector

    // XCD-aware bijective swizzle (GRID % 8 == 0): contiguous col range per XCD
    const int b  = blockIdx.x;
    const int bs = (b & 7) * (GRID / 8) + (b >> 3);
    const int col0 = bs * (NCH * 256) + w * 32 + q;

    // ---------- X fragments for all chunks, kept in registers ----------
    half8 bf[NCH][4];
    float hx2[NCH];
    #pragma unroll
    for (int ch = 0; ch < NCH; ++ch) {
        const float* xr = X + (size_t)(col0 + ch * 256) * DD;
        float p = 0.f;
        #pragma unroll
        for (int kk = 0; kk < 4; ++kk) {
            float4 v0 = *(const float4*)(xr + kk * 16 + h * 8);
            float4 v1 = *(const float4*)(xr + kk * 16 + h * 8 + 4);
            p += v0.x*v0.x + v0.y*v0.y + v0.z*v0.z + v0.w*v0.w
               + v1.x*v1.x + v1.y*v1.y + v1.z*v1.z + v1.w*v1.w;
            bf[ch][kk] = { (_Float16)v0.x, (_Float16)v0.y, (_Float16)v0.z, (_Float16)v0.w,
                           (_Float16)v1.x, (_Float16)v1.y, (_Float16)v1.z, (_Float16)v1.w };
        }
        p += __shfl_xor(p, 32, 64);   // partner lane holds the other k-half
        hx2[ch] = 0.5f * p;
    }
    __syncthreads();

    #pragma unroll 1
    for (int c = 0; c < 8; ++c) {
        // keep the 8 waves slot-aligned: their simultaneous stores form the
        // 1-KB cross-wave line groups / 4-KB row bursts (R9 showed footprint
        // coherence matters; without a barrier the waves drift over 512 stores)
        __syncthreads();

        const unsigned rbase = (unsigned)(32 * c + q) * 128u;
        const unsigned sw = (unsigned)(q & 7);
        half8 af[4];
        #pragma unroll
        for (int kk = 0; kk < 4; ++kk)
            af[kk] = *(const half8*)(smu + rbase + ((((unsigned)(2 * kk + h)) ^ sw) * 16));

        f32x16 acc[NCH];
        #pragma unroll
        for (int ch = 0; ch < NCH; ++ch) {
            acc[ch] = (f32x16){0.f,0.f,0.f,0.f,0.f,0.f,0.f,0.f,
                               0.f,0.f,0.f,0.f,0.f,0.f,0.f,0.f};
            #pragma unroll
            for (int kk = 0; kk < 4; ++kk)
                acc[ch] = __builtin_amdgcn_mfma_f32_32x32x16_f16(af[kk], bf[ch][kk], acc[ch], 0, 0, 0);
        }

        // D layout: col = lane&31, row = (reg&3) + 8*(reg>>2) + 4*(lane>>5)
        // full-line stores in (g, j, ch) order -> 4-KB burst per k-row per block;
        // nontemporal: stream past L2, preserve burst order, don't evict X
        #pragma unroll
        for (int g = 0; g < 4; ++g) {
            const int Rb = 32 * c + 8 * g + 4 * h;
            #pragma unroll
            for (int j = 0; j < 4; ++j) {
                const float2 ac = AC[Rb + j];
                float* po = out + (size_t)(Rb + j) * NN + col0;
                #pragma unroll
                for (int ch = 0; ch < NCH; ++ch)
                    __builtin_nontemporal_store(
                        ac.x + (acc[ch][4 * g + j] - hx2[ch]) * ac.y, &po[ch * 256]);
            }
        }
    }
}

extern "C" void kernel_launch(void* const* d_in, const int* in_sizes, int n_in,
                              void* d_out, int out_size, void* d_ws, size_t ws_size,
                              hipStream_t stream)
{
    const float* X  = (const float*)d_in[0];
    const float* mu = (const float*)d_in[1];
    const float* lv = (const float*)d_in[2];
    const float* al = (const float*)d_in[3];
    float* out = (float*)d_out;
    gmm_ll_kernel<<<GRID, 512, 0, stream>>>(X, mu, lv, al, out);
}

// Round 13
// 64.247 us; speedup vs baseline: 1.1849x; 1.0149x over previous
//
#include <hip/hip_runtime.h>
#include <hip/hip_bf16.h>

typedef _Float16 half8 __attribute__((ext_vector_type(8)));
typedef float f32x16 __attribute__((ext_vector_type(16)));

constexpr int KC = 256;      // clusters
constexpr int DD = 64;       // feature dim
constexpr int NN = 262144;   // points
constexpr int GRID = 256;    // blocks; each owns NCH*256 = 1024 cols
constexpr int NCH = 4;       // column chunks per block

// out[k][n] = A[k] + (mu[k].x[n] - 0.5*x2[n]) * C[k]
// A[k] = alpha[k] - 32*logvar[k] - 0.5*m2[k]*C[k],  C[k] = exp(-logvar[k])

__global__ __launch_bounds__(512, 2)
void gmm_ll_kernel(const float* __restrict__ X,
                   const float* __restrict__ mu,
                   const float* __restrict__ logvar,
                   const float* __restrict__ alpha,
                   float* __restrict__ out)
{
    // mu in f16, XOR-swizzled chunks: row r (128 B = 8 chunks), chunk s at slot s^(r&7)
    __shared__ __align__(16) unsigned char smu[KC * 128];
    __shared__ float2 AC[KC];

    const int tid = threadIdx.x;

    // ---------- setup: threads 0..255 own one cluster each ----------
    if (tid < KC) {
        const float* mrow = mu + tid * DD;
        float m2 = 0.f;
        #pragma unroll
        for (int s = 0; s < 8; ++s) {
            float4 v0 = *(const float4*)(mrow + 8 * s);
            float4 v1 = *(const float4*)(mrow + 8 * s + 4);
            m2 += v0.x*v0.x + v0.y*v0.y + v0.z*v0.z + v0.w*v0.w
                + v1.x*v1.x + v1.y*v1.y + v1.z*v1.z + v1.w*v1.w;
            half8 hch = { (_Float16)v0.x, (_Float16)v0.y, (_Float16)v0.z, (_Float16)v0.w,
                          (_Float16)v1.x, (_Float16)v1.y, (_Float16)v1.z, (_Float16)v1.w };
            *(half8*)(smu + tid * 128 + ((s ^ (tid & 7)) * 16)) = hch;
        }
        float lv = logvar[tid];
        float Cv = __expf(-lv);
        AC[tid] = make_float2(alpha[tid] - 32.0f * lv - 0.5f * m2 * Cv, Cv);
    }

    const int l = tid & 63;
    const int w = tid >> 6;   // wave 0..7
    const int q = l & 31;     // column within 32-col window / mu row selector
    const int h = l >> 5;     // k-half selector

    // XCD-aware bijective swizzle (GRID % 8 == 0): contiguous col range per XCD
    const int b  = blockIdx.x;
    const int bs = (b & 7) * (GRID / 8) + (b >> 3);
    const int col0 = bs * (NCH * 256) + w * 32 + q;

    // ---------- X fragments for all chunks, kept in registers ----------
    half8 bf[NCH][4];
    float hx2[NCH];
    #pragma unroll
    for (int ch = 0; ch < NCH; ++ch) {
        const float* xr = X + (size_t)(col0 + ch * 256) * DD;
        float p = 0.f;
        #pragma unroll
        for (int kk = 0; kk < 4; ++kk) {
            float4 v0 = *(const float4*)(xr + kk * 16 + h * 8);
            float4 v1 = *(const float4*)(xr + kk * 16 + h * 8 + 4);
            p += v0.x*v0.x + v0.y*v0.y + v0.z*v0.z + v0.w*v0.w
               + v1.x*v1.x + v1.y*v1.y + v1.z*v1.z + v1.w*v1.w;
            bf[ch][kk] = { (_Float16)v0.x, (_Float16)v0.y, (_Float16)v0.z, (_Float16)v0.w,
                           (_Float16)v1.x, (_Float16)v1.y, (_Float16)v1.z, (_Float16)v1.w };
        }
        p += __shfl_xor(p, 32, 64);   // partner lane holds the other k-half
        hx2[ch] = 0.5f * p;
    }
    __syncthreads();

    #pragma unroll 1
    for (int c = 0; c < 8; ++c) {
        // re-align the 8 waves each c-phase (R12: +2.7 us) — their simultaneous
        // stores form 1-KB cross-wave line groups / 4-KB row bursts
        __syncthreads();

        const unsigned rbase = (unsigned)(32 * c + q) * 128u;
        const unsigned sw = (unsigned)(q & 7);
        half8 af[4];
        #pragma unroll
        for (int kk = 0; kk < 4; ++kk)
            af[kk] = *(const half8*)(smu + rbase + ((((unsigned)(2 * kk + h)) ^ sw) * 16));

        f32x16 acc[NCH];
        #pragma unroll
        for (int ch = 0; ch < NCH; ++ch) {
            acc[ch] = (f32x16){0.f,0.f,0.f,0.f,0.f,0.f,0.f,0.f,
                               0.f,0.f,0.f,0.f,0.f,0.f,0.f,0.f};
            #pragma unroll
            for (int kk = 0; kk < 4; ++kk)
                acc[ch] = __builtin_amdgcn_mfma_f32_32x32x16_f16(af[kk], bf[ch][kk], acc[ch], 0, 0, 0);
        }

        // D layout: col = lane&31, row = (reg&3) + 8*(reg>>2) + 4*(lane>>5)
        // full-line nt-stores in (g, j, ch) order -> 4-KB burst per k-row;
        // raw s_barrier between g-subphases: within-phase re-alignment
        // without the vmcnt(0) drain (smu/AC read-only -> no data hazard)
        #pragma unroll
        for (int g = 0; g < 4; ++g) {
            if (g) __builtin_amdgcn_s_barrier();
            const int Rb = 32 * c + 8 * g + 4 * h;
            #pragma unroll
            for (int j = 0; j < 4; ++j) {
                const float2 ac = AC[Rb + j];
                float* po = out + (size_t)(Rb + j) * NN + col0;
                #pragma unroll
                for (int ch = 0; ch < NCH; ++ch)
                    __builtin_nontemporal_store(
                        ac.x + (acc[ch][4 * g + j] - hx2[ch]) * ac.y, &po[ch * 256]);
            }
        }
    }
}

extern "C" void kernel_launch(void* const* d_in, const int* in_sizes, int n_in,
                              void* d_out, int out_size, void* d_ws, size_t ws_size,
                              hipStream_t stream)
{
    const float* X  = (const float*)d_in[0];
    const float* mu = (const float*)d_in[1];
    const float* lv = (const float*)d_in[2];
    const float* al = (const float*)d_in[3];
    float* out = (float*)d_out;
    gmm_ll_kernel<<<GRID, 512, 0, stream>>>(X, mu, lv, al, out);
}

// Round 14
// 63.928 us; speedup vs baseline: 1.1908x; 1.0050x over previous
//
#include <hip/hip_runtime.h>
#include <hip/hip_bf16.h>

typedef _Float16 half8 __attribute__((ext_vector_type(8)));
typedef float f32x16 __attribute__((ext_vector_type(16)));

constexpr int KC = 256;      // clusters
constexpr int DD = 64;       // feature dim
constexpr int NN = 262144;   // points
constexpr int GRID = 256;    // blocks; each owns NCH*256 = 1024 cols
constexpr int NCH = 4;       // column chunks per block

// out[k][n] = A[k] + (mu[k].x[n] - 0.5*x2[n]) * C[k]
// A[k] = alpha[k] - 32*logvar[k] - 0.5*m2[k]*C[k],  C[k] = exp(-logvar[k])

__global__ __launch_bounds__(512, 2)
void gmm_ll_kernel(const float* __restrict__ X,
                   const float* __restrict__ mu,
                   const float* __restrict__ logvar,
                   const float* __restrict__ alpha,
                   float* __restrict__ out)
{
    // mu in f16, XOR-swizzled chunks: row r (128 B = 8 chunks), chunk s at slot s^(r&7)
    __shared__ __align__(16) unsigned char smu[KC * 128];
    __shared__ float2 AC[KC];

    const int tid = threadIdx.x;

    // ---------- setup: threads 0..255 own one cluster each ----------
    if (tid < KC) {
        const float* mrow = mu + tid * DD;
        float m2 = 0.f;
        #pragma unroll
        for (int s = 0; s < 8; ++s) {
            float4 v0 = *(const float4*)(mrow + 8 * s);
            float4 v1 = *(const float4*)(mrow + 8 * s + 4);
            m2 += v0.x*v0.x + v0.y*v0.y + v0.z*v0.z + v0.w*v0.w
                + v1.x*v1.x + v1.y*v1.y + v1.z*v1.z + v1.w*v1.w;
            half8 hch = { (_Float16)v0.x, (_Float16)v0.y, (_Float16)v0.z, (_Float16)v0.w,
                          (_Float16)v1.x, (_Float16)v1.y, (_Float16)v1.z, (_Float16)v1.w };
            *(half8*)(smu + tid * 128 + ((s ^ (tid & 7)) * 16)) = hch;
        }
        float lv = logvar[tid];
        float Cv = __expf(-lv);
        AC[tid] = make_float2(alpha[tid] - 32.0f * lv - 0.5f * m2 * Cv, Cv);
    }

    const int l = tid & 63;
    const int w = tid >> 6;   // wave 0..7
    const int q = l & 31;     // column within 32-col window / mu row selector
    const int h = l >> 5;     // k-half selector

    // XCD-aware bijective swizzle (GRID % 8 == 0): contiguous col range per XCD
    const int b  = blockIdx.x;
    const int bs = (b & 7) * (GRID / 8) + (b >> 3);
    const int col0 = bs * (NCH * 256) + w * 32 + q;

    // ---------- X fragments for all chunks, kept in registers ----------
    half8 bf[NCH][4];
    float hx2[NCH];
    #pragma unroll
    for (int ch = 0; ch < NCH; ++ch) {
        const float* xr = X + (size_t)(col0 + ch * 256) * DD;
        float p = 0.f;
        #pragma unroll
        for (int kk = 0; kk < 4; ++kk) {
            float4 v0 = *(const float4*)(xr + kk * 16 + h * 8);
            float4 v1 = *(const float4*)(xr + kk * 16 + h * 8 + 4);
            p += v0.x*v0.x + v0.y*v0.y + v0.z*v0.z + v0.w*v0.w
               + v1.x*v1.x + v1.y*v1.y + v1.z*v1.z + v1.w*v1.w;
            bf[ch][kk] = { (_Float16)v0.x, (_Float16)v0.y, (_Float16)v0.z, (_Float16)v0.w,
                           (_Float16)v1.x, (_Float16)v1.y, (_Float16)v1.z, (_Float16)v1.w };
        }
        p += __shfl_xor(p, 32, 64);   // partner lane holds the other k-half
        hx2[ch] = 0.5f * p;
    }
    __syncthreads();

    #pragma unroll 1
    for (int c = 0; c < 8; ++c) {
        // re-align the 8 waves each c-phase (R12: +2.7 us)
        __syncthreads();

        const unsigned rbase = (unsigned)(32 * c + q) * 128u;
        const unsigned sw = (unsigned)(q & 7);
        half8 af[4];
        #pragma unroll
        for (int kk = 0; kk < 4; ++kk)
            af[kk] = *(const half8*)(smu + rbase + ((((unsigned)(2 * kk + h)) ^ sw) * 16));

        f32x16 acc[NCH];
        #pragma unroll
        for (int ch = 0; ch < NCH; ++ch) {
            acc[ch] = (f32x16){0.f,0.f,0.f,0.f,0.f,0.f,0.f,0.f,
                               0.f,0.f,0.f,0.f,0.f,0.f,0.f,0.f};
            #pragma unroll
            for (int kk = 0; kk < 4; ++kk)
                acc[ch] = __builtin_amdgcn_mfma_f32_32x32x16_f16(af[kk], bf[ch][kk], acc[ch], 0, 0, 0);
        }

        // D layout: col = lane&31, row = (reg&3) + 8*(reg>>2) + 4*(lane>>5)
        // full-line nt-stores in (g, j, ch) order -> 4-KB burst per k-row;
        // per-g DRAIN + barrier: each 16-KB/block row-group retires fully
        // before the next opens (R12 mechanism = drain-batching, pushed to
        // g granularity; R13 raw barriers aligned but did not drain)
        #pragma unroll
        for (int g = 0; g < 4; ++g) {
            if (g) {
                asm volatile("s_waitcnt vmcnt(0)" ::: "memory");
                __builtin_amdgcn_s_barrier();
            }
            const int Rb = 32 * c + 8 * g + 4 * h;
            #pragma unroll
            for (int j = 0; j < 4; ++j) {
                const float2 ac = AC[Rb + j];
                float* po = out + (size_t)(Rb + j) * NN + col0;
                #pragma unroll
                for (int ch = 0; ch < NCH; ++ch)
                    __builtin_nontemporal_store(
                        ac.x + (acc[ch][4 * g + j] - hx2[ch]) * ac.y, &po[ch * 256]);
            }
        }
    }
}

extern "C" void kernel_launch(void* const* d_in, const int* in_sizes, int n_in,
                              void* d_out, int out_size, void* d_ws, size_t ws_size,
                              hipStream_t stream)
{
    const float* X  = (const float*)d_in[0];
    const float* mu = (const float*)d_in[1];
    const float* lv = (const float*)d_in[2];
    const float* al = (const float*)d_in[3];
    float* out = (float*)d_out;
    gmm_ll_kernel<<<GRID, 512, 0, stream>>>(X, mu, lv, al, out);
}